// Round 1
// baseline (1167.233 us; speedup 1.0000x reference)
//
#include <hip/hip_runtime.h>
#include <math.h>

// TriangleAttention, fused single kernel.
// B=2, L=256, D=64, H=4, Dh=16.
// Block = 256 threads = one (b,l) row; thread p owns position p.
// Attention for row (b,l) only mixes positions within that row -> block-local.

static constexpr int TB  = 2;
static constexpr int TL  = 256;
static constexpr int TD  = 64;
static constexpr int TH  = 4;
static constexpr int TDH = 16;
static constexpr int KV_STRIDE = TDH + 1;  // 17: coprime with 32 banks -> conflict-free writes

__global__ __launch_bounds__(256, 2)
void triattn_kernel(const float* __restrict__ z,
                    const float* __restrict__ ln_scale,
                    const float* __restrict__ ln_bias,
                    const float* __restrict__ Wq,
                    const float* __restrict__ Wk,
                    const float* __restrict__ Wv,
                    const float* __restrict__ Wg,
                    const float* __restrict__ bg,
                    const float* __restrict__ Wo,
                    const float* __restrict__ bo,
                    float* __restrict__ out)
{
    const int p  = threadIdx.x;                  // position within row, 0..255
    const int bl = blockIdx.x;                   // b*L + l
    const size_t rowbase = (size_t)bl * TL * TD; // offset of z[b,l,0,0]

    __shared__ float Ksh[TL * KV_STRIDE];
    __shared__ float Vsh[TL * KV_STRIDE];

    // ---- load z[b,l,p,:] and LayerNorm in registers ----
    float zn[TD];
    const float* zp = z + rowbase + (size_t)p * TD;
    float mean = 0.f;
    #pragma unroll
    for (int k = 0; k < TD; ++k) { zn[k] = zp[k]; mean += zn[k]; }
    mean *= (1.0f / TD);
    float var = 0.f;
    #pragma unroll
    for (int k = 0; k < TD; ++k) { float d = zn[k] - mean; var += d * d; }
    var *= (1.0f / TD);
    const float rstd = rsqrtf(var + 1e-5f);
    #pragma unroll
    for (int k = 0; k < TD; ++k)
        zn[k] = (zn[k] - mean) * rstd * ln_scale[k] + ln_bias[k];

    // final (gated, Wo-projected) accumulator for output row p
    float facc[TD];
    #pragma unroll
    for (int d = 0; d < TD; ++d) facc[d] = 0.f;

    const float qscale = 0.25f;  // 1/sqrt(Dh)

    for (int h = 0; h < TH; ++h) {
        // ---- project this head's K,V slices into LDS; Q slice into regs ----
        float q[TDH];
        #pragma unroll
        for (int dh = 0; dh < TDH; ++dh) {
            const int ch = h * TDH + dh;                 // channel index in D
            const float* wq = Wq + (size_t)ch * TD;      // wave-uniform -> s_load
            const float* wk = Wk + (size_t)ch * TD;
            const float* wv = Wv + (size_t)ch * TD;
            float sq = 0.f, sk = 0.f, sv = 0.f;
            #pragma unroll
            for (int k = 0; k < TD; ++k) {
                sq += zn[k] * wq[k];
                sk += zn[k] * wk[k];
                sv += zn[k] * wv[k];
            }
            Ksh[p * KV_STRIDE + dh] = sk;
            Vsh[p * KV_STRIDE + dh] = sv;
            q[dh] = sq * qscale;
        }
        __syncthreads();

        // ---- online-softmax attention: thread p is query i=p ----
        float m = -1e30f, lsum = 0.f;
        float o[TDH];
        #pragma unroll
        for (int dh = 0; dh < TDH; ++dh) o[dh] = 0.f;

        for (int j = 0; j < TL; ++j) {
            float s = 0.f;
            #pragma unroll
            for (int dh = 0; dh < TDH; ++dh)
                s += q[dh] * Ksh[j * KV_STRIDE + dh];     // broadcast read
            const float mnew  = fmaxf(m, s);
            const float alpha = __expf(m - mnew);         // first iter: exp(-huge)=0
            const float pexp  = __expf(s - mnew);
            lsum = lsum * alpha + pexp;
            #pragma unroll
            for (int dh = 0; dh < TDH; ++dh)
                o[dh] = o[dh] * alpha + pexp * Vsh[j * KV_STRIDE + dh];
            m = mnew;
        }
        const float inv_l = 1.0f / lsum;

        // ---- gate this head's channels, fold into Wo projection ----
        #pragma unroll
        for (int dh = 0; dh < TDH; ++dh) {
            const int ch = h * TDH + dh;
            const float* wg = Wg + (size_t)ch * TD;
            float sg = bg[ch];
            #pragma unroll
            for (int k = 0; k < TD; ++k) sg += zn[k] * wg[k];
            const float gate = 1.0f / (1.0f + __expf(-sg));
            const float go = gate * o[dh] * inv_l;
            #pragma unroll
            for (int d = 0; d < TD; ++d)
                facc[d] += Wo[(size_t)d * TD + ch] * go;   // wave-uniform Wo -> s_load
        }
        __syncthreads();  // Ksh/Vsh reused by next head
    }

    // ---- write out[b,l,p,:] ----
    float* op = out + rowbase + (size_t)p * TD;
    #pragma unroll
    for (int d = 0; d < TD; ++d) op[d] = facc[d] + bo[d];
}

extern "C" void kernel_launch(void* const* d_in, const int* in_sizes, int n_in,
                              void* d_out, int out_size, void* d_ws, size_t ws_size,
                              hipStream_t stream) {
    const float* z  = (const float*)d_in[0];
    const float* ls = (const float*)d_in[1];
    const float* lb = (const float*)d_in[2];
    const float* Wq = (const float*)d_in[3];
    const float* Wk = (const float*)d_in[4];
    const float* Wv = (const float*)d_in[5];
    const float* Wg = (const float*)d_in[6];
    const float* bg = (const float*)d_in[7];
    const float* Wo = (const float*)d_in[8];
    const float* bo = (const float*)d_in[9];
    float* out = (float*)d_out;

    dim3 grid(TB * TL);   // 512 row-blocks
    dim3 block(TL);       // 256 threads, one per position
    hipLaunchKernelGGL(triattn_kernel, grid, block, 0, stream,
                       z, ls, lb, Wq, Wk, Wv, Wg, bg, Wo, bo, out);
}

// Round 2
// 318.965 us; speedup vs baseline: 3.6594x; 3.6594x over previous
//
#include <hip/hip_runtime.h>
#include <math.h>

// TriangleAttention — bf16 MFMA implementation.
// B=2, L=256, D=64, H=4, Dh=16. Block = 256 threads (4 waves) = one (b,l) row.
// Per head: LN->ZN(bf16) -> Q/K/V/G projections (mfma 16x16x32) ->
// two-pass exact softmax (unnormalized P, 1/l folded into epilogue) ->
// PV (mfma, P via LDS A-layout round trip) -> gate*O -> Wo projection
// accumulated in registers across heads.
//
// mfma_f32_16x16x32_bf16 layouts (verified in docs):
//   A[m = lane&15][k = (lane>>4)*8 + u]   (8 bf16 per lane)
//   B[k = (lane>>4)*8 + u][n = lane&15]
//   C/D: col = lane&15, row = (lane>>4)*4 + reg
// Dh=16 < K=32: quads 2,3 read a zeroed 16B LDS line (address cndmask).

typedef __attribute__((ext_vector_type(4))) float f32x4;
typedef __attribute__((ext_vector_type(8))) short s16x8;

#define MFMA16(a, b, c) __builtin_amdgcn_mfma_f32_16x16x32_bf16((a), (b), (c), 0, 0, 0)

static constexpr int TL = 256, TD = 64, TH = 4;

// LDS map (units: shorts). Total 31752 el = 63504 B < 64 KB -> 2 blocks/CU.
static constexpr int ZNP   = 0;      // [256][64] XOR-swizzled: zn bf16, then P bf16
static constexpr int QHO   = 16384;  // [256][16] row-major: Qh, then gated-O
static constexpr int KHB   = 20480;  // [256][16] 2-block swizzle: Kh
static constexpr int VTB   = 24576;  // [16][256] XOR-swizzled: V transposed
static constexpr int WBUF0 = 28672;  // [16][64] XOR-swizzled (Wq then Wv)
static constexpr int WBUF1 = 29696;  // [16][64] XOR-swizzled (Wk then Wg)
static constexpr int WOB   = 30720;  // [64][16] 2-block swizzle: Wo head slice
static constexpr int ZLINE = 31744;  // 8 zero shorts (16 B)
static constexpr int LDS_EL = 31752;

__device__ __forceinline__ short f2bf(float x) {   // fp32 -> bf16 RNE
    union { float f; unsigned u; } v; v.f = x;
    unsigned r = v.u + 0x7fffu + ((v.u >> 16) & 1u);
    return (short)(r >> 16);
}

__global__ __launch_bounds__(256, 2)
void triattn_mfma(const float* __restrict__ z,  const float* __restrict__ ln_s,
                  const float* __restrict__ ln_b, const float* __restrict__ Wq,
                  const float* __restrict__ Wk, const float* __restrict__ Wv,
                  const float* __restrict__ Wg, const float* __restrict__ bg,
                  const float* __restrict__ Wo, const float* __restrict__ bo,
                  float* __restrict__ out)
{
    __shared__ __align__(16) short lds[LDS_EL];
    const int tid  = threadIdx.x;
    const int lane = tid & 63;
    const int w    = tid >> 6;
    const int n16  = lane & 15;
    const int quad = lane >> 4;
    const bool qlo = (quad < 2);
    const int w64  = w * 64;
    const size_t rowbase = (size_t)blockIdx.x * (TL * TD);

    f32x4 oacc[4][4];
    #pragma unroll
    for (int a = 0; a < 4; ++a)
        #pragma unroll
        for (int b = 0; b < 4; ++b) oacc[a][b] = {};

    if (tid == 0) { s16x8 zz = {}; *(s16x8*)&lds[ZLINE] = zz; }  // ordered by B2 below

    for (int h = 0; h < TH; ++h) {
        __syncthreads();                                    // B1: prev head fully done
        // ---------------- LN -> ZN (bf16, swizzled) ----------------
        {
            float zn[64];
            const float* zp = z + rowbase + (size_t)tid * 64;
            float mu = 0.f;
            #pragma unroll
            for (int k = 0; k < 64; ++k) { zn[k] = zp[k]; mu += zn[k]; }
            mu *= (1.f / 64.f);
            float va = 0.f;
            #pragma unroll
            for (int k = 0; k < 64; ++k) { float d = zn[k] - mu; va += d * d; }
            const float rs = rsqrtf(va * (1.f / 64.f) + 1e-5f);
            #pragma unroll
            for (int k = 0; k < 64; ++k) zn[k] = (zn[k] - mu) * rs * ln_s[k] + ln_b[k];
            #pragma unroll
            for (int g = 0; g < 8; ++g) {
                s16x8 v;
                #pragma unroll
                for (int u = 0; u < 8; ++u) v[u] = f2bf(zn[g * 8 + u]);
                *(s16x8*)&lds[ZNP + tid * 64 + ((g ^ (tid & 7)) * 8)] = v;
            }
        }
        // ---------------- W head-slices -> bf16 LDS ----------------
        // Wq/Wk/Wv/Wg: rows [h*16, h*16+16), all 64 cols. 1024 el / 256 thr = 4 each.
        {
            #pragma unroll
            for (int e = 0; e < 4; ++e) {
                int flat = e * 256 + tid, r = flat >> 6, c = flat & 63;
                int sw = ((c >> 3) ^ (r & 7)) * 8 + (c & 7);
                lds[WBUF0 + r * 64 + sw] = f2bf(Wq[(h * 16 + r) * 64 + c]);
                lds[WBUF1 + r * 64 + sw] = f2bf(Wk[(h * 16 + r) * 64 + c]);
            }
        }
        __syncthreads();                                    // B2: ZN + Wq/Wk visible

        // projection helper: C[256 x 16] = ZN[256 x 64] @ Wbuf^T, wave's 4 M-tiles
        auto projA = [&](int wbuf, int mt) -> f32x4 {
            f32x4 acc = {};
            #pragma unroll
            for (int ks = 0; ks < 2; ++ks) {
                int sw = (((ks * 4 + quad) ^ (n16 & 7)) * 8);
                s16x8 a = *(const s16x8*)&lds[ZNP + (w64 + mt * 16 + n16) * 64 + sw];
                s16x8 b = *(const s16x8*)&lds[wbuf + n16 * 64 + sw];
                acc = MFMA16(a, b, acc);
            }
            return acc;
        };

        // ---- Q (scaled 1/sqrt(Dh)) -> QHO, K -> KHB ----
        #pragma unroll
        for (int mt = 0; mt < 4; ++mt) {
            f32x4 q = projA(WBUF0, mt);
            #pragma unroll
            for (int r = 0; r < 4; ++r)
                lds[QHO + (w64 + mt * 16 + quad * 4 + r) * 16 + n16] = f2bf(0.25f * q[r]);
        }
        #pragma unroll
        for (int mt = 0; mt < 4; ++mt) {
            f32x4 kk = projA(WBUF1, mt);
            #pragma unroll
            for (int r = 0; r < 4; ++r) {
                int i = w64 + mt * 16 + quad * 4 + r;
                lds[KHB + i * 16 + (((n16 >> 3) ^ (i & 1)) * 8) + (n16 & 7)] = f2bf(kk[r]);
            }
        }
        __syncthreads();                                    // B3: Q/K proj reads done
        {
            #pragma unroll
            for (int e = 0; e < 4; ++e) {
                int flat = e * 256 + tid, r = flat >> 6, c = flat & 63;
                int sw = ((c >> 3) ^ (r & 7)) * 8 + (c & 7);
                lds[WBUF0 + r * 64 + sw] = f2bf(Wv[(h * 16 + r) * 64 + c]);
                lds[WBUF1 + r * 64 + sw] = f2bf(Wg[(h * 16 + r) * 64 + c]);
            }
            #pragma unroll
            for (int e = 0; e < 4; ++e) {                   // Wo slice: [64][16]
                int flat = e * 256 + tid, r = flat >> 4, c = flat & 15;
                lds[WOB + r * 16 + (((c >> 3) ^ (r & 1)) * 8) + (c & 7)] =
                    f2bf(Wo[r * 64 + h * 16 + c]);
            }
        }
        __syncthreads();                                    // B4: Wv/Wg/Wo visible
        // ---- V -> VTB (transposed), G -> regs ----
        #pragma unroll
        for (int mt = 0; mt < 4; ++mt) {
            f32x4 vv = projA(WBUF0, mt);
            #pragma unroll
            for (int r = 0; r < 4; ++r) {
                int j = w64 + mt * 16 + quad * 4 + r;
                lds[VTB + n16 * 256 + (((j >> 3) ^ (n16 & 7)) * 8) + (j & 7)] = f2bf(vv[r]);
            }
        }
        f32x4 g4[4];
        {
            float gb = bg[h * 16 + n16];
            #pragma unroll
            for (int mt = 0; mt < 4; ++mt) {
                f32x4 gg = projA(WBUF1, mt);
                #pragma unroll
                for (int r = 0; r < 4; ++r)
                    g4[mt][r] = 1.f / (1.f + __expf(-(gg[r] + gb)));
            }
        }
        __syncthreads();                                    // B5: Kh/Vt visible everywhere

        // ---------------- attention ----------------
        s16x8 qa[4];
        #pragma unroll
        for (int mt = 0; mt < 4; ++mt) {
            int off = qlo ? (QHO + (w64 + mt * 16 + n16) * 16 + quad * 8) : ZLINE;
            qa[mt] = *(const s16x8*)&lds[off];
        }
        float mrow[4][4], lrow[4][4];
        #pragma unroll
        for (int mt = 0; mt < 4; ++mt)
            #pragma unroll
            for (int r = 0; r < 4; ++r) { mrow[mt][r] = -3.0e38f; lrow[mt][r] = 0.f; }

        // pass 1: exact row max (S discarded)
        for (int jt = 0; jt < 16; ++jt) {
            int j = jt * 16 + n16;
            int off = qlo ? (KHB + j * 16 + ((quad ^ (n16 & 1)) * 8)) : ZLINE;
            s16x8 kb = *(const s16x8*)&lds[off];
            #pragma unroll
            for (int mt = 0; mt < 4; ++mt) {
                f32x4 zc = {};
                f32x4 s = MFMA16(qa[mt], kb, zc);
                #pragma unroll
                for (int r = 0; r < 4; ++r) mrow[mt][r] = fmaxf(mrow[mt][r], s[r]);
            }
        }
        #pragma unroll
        for (int d = 1; d < 16; d <<= 1)
            #pragma unroll
            for (int mt = 0; mt < 4; ++mt)
                #pragma unroll
                for (int r = 0; r < 4; ++r)
                    mrow[mt][r] = fmaxf(mrow[mt][r], __shfl_xor(mrow[mt][r], d));

        // pass 2: recompute S, P = exp(s - m) (unnormalized) -> LDS, PV in 64-j chunks
        f32x4 o4[4];
        #pragma unroll
        for (int mt = 0; mt < 4; ++mt) o4[mt] = {};
        for (int ch = 0; ch < 4; ++ch) {
            #pragma unroll
            for (int jtl = 0; jtl < 4; ++jtl) {
                int j = (ch * 4 + jtl) * 16 + n16;
                int off = qlo ? (KHB + j * 16 + ((quad ^ (n16 & 1)) * 8)) : ZLINE;
                s16x8 kb = *(const s16x8*)&lds[off];
                #pragma unroll
                for (int mt = 0; mt < 4; ++mt) {
                    f32x4 zc = {};
                    f32x4 s = MFMA16(qa[mt], kb, zc);
                    #pragma unroll
                    for (int r = 0; r < 4; ++r) {
                        float e = __expf(s[r] - mrow[mt][r]);
                        lrow[mt][r] += e;
                        int i = w64 + mt * 16 + quad * 4 + r;
                        int blk = jtl * 2 + (n16 >> 3);
                        lds[ZNP + i * 64 + (((blk ^ (i & 7)) * 8)) + (n16 & 7)] = f2bf(e);
                    }
                }
            }
            #pragma unroll
            for (int ks = 0; ks < 2; ++ks) {
                int blkv = ch * 8 + ks * 4 + quad;
                s16x8 vb = *(const s16x8*)&lds[VTB + n16 * 256 + (((blkv ^ (n16 & 7)) * 8))];
                #pragma unroll
                for (int mt = 0; mt < 4; ++mt) {
                    int sw = (((ks * 4 + quad) ^ (n16 & 7)) * 8);
                    s16x8 pa = *(const s16x8*)&lds[ZNP + (w64 + mt * 16 + n16) * 64 + sw];
                    o4[mt] = MFMA16(pa, vb, o4[mt]);
                }
            }
        }
        #pragma unroll
        for (int d = 1; d < 16; d <<= 1)
            #pragma unroll
            for (int mt = 0; mt < 4; ++mt)
                #pragma unroll
                for (int r = 0; r < 4; ++r)
                    lrow[mt][r] += __shfl_xor(lrow[mt][r], d);

        // ---- gated O (x 1/l) -> bf16 A-layout (reuse QHO), Wo projection ----
        #pragma unroll
        for (int mt = 0; mt < 4; ++mt)
            #pragma unroll
            for (int r = 0; r < 4; ++r) {
                float go = g4[mt][r] * o4[mt][r] / lrow[mt][r];
                lds[QHO + (w64 + mt * 16 + quad * 4 + r) * 16 + n16] = f2bf(go);
            }
        s16x8 wob[4];
        #pragma unroll
        for (int nt = 0; nt < 4; ++nt) {
            int od = nt * 16 + n16;
            int off = qlo ? (WOB + od * 16 + ((quad ^ (od & 1)) * 8)) : ZLINE;
            wob[nt] = *(const s16x8*)&lds[off];
        }
        #pragma unroll
        for (int mt = 0; mt < 4; ++mt) {
            int off = qlo ? (QHO + (w64 + mt * 16 + n16) * 16 + quad * 8) : ZLINE;
            s16x8 goa = *(const s16x8*)&lds[off];
            #pragma unroll
            for (int nt = 0; nt < 4; ++nt)
                oacc[mt][nt] = MFMA16(goa, wob[nt], oacc[mt][nt]);
        }
    } // heads

    // ---------------- epilogue: + bo, store ----------------
    #pragma unroll
    for (int nt = 0; nt < 4; ++nt) {
        float bov = bo[nt * 16 + n16];
        #pragma unroll
        for (int mt = 0; mt < 4; ++mt)
            #pragma unroll
            for (int r = 0; r < 4; ++r) {
                int row = w64 + mt * 16 + quad * 4 + r;
                out[rowbase + (size_t)row * 64 + nt * 16 + n16] = oacc[mt][nt][r] + bov;
            }
    }
}

extern "C" void kernel_launch(void* const* d_in, const int* in_sizes, int n_in,
                              void* d_out, int out_size, void* d_ws, size_t ws_size,
                              hipStream_t stream) {
    const float* z  = (const float*)d_in[0];
    const float* ls = (const float*)d_in[1];
    const float* lb = (const float*)d_in[2];
    const float* Wq = (const float*)d_in[3];
    const float* Wk = (const float*)d_in[4];
    const float* Wv = (const float*)d_in[5];
    const float* Wg = (const float*)d_in[6];
    const float* bg = (const float*)d_in[7];
    const float* Wo = (const float*)d_in[8];
    const float* bo = (const float*)d_in[9];
    float* out = (float*)d_out;

    hipLaunchKernelGGL(triattn_mfma, dim3(2 * TL), dim3(256), 0, stream,
                       z, ls, lb, Wq, Wk, Wv, Wg, bg, Wo, bo, out);
}

// Round 3
// 260.062 us; speedup vs baseline: 4.4883x; 1.2265x over previous
//
#include <hip/hip_runtime.h>
#include <math.h>

// TriangleAttention — 3-kernel pipeline, bf16 MFMA.
// B=2, L=256, D=64, H=4, Dh=16.
// k1: LN + Q/K/V/G projections -> ws (bf16)
// k2: per-(row,head) attention (two-pass softmax) -> gated O (bf16) -> ws
// k3: GO @ Wo^T + bo -> out (fp32)
//
// mfma_f32_16x16x32_bf16 layouts (verified round 2):
//   A[m = lane&15][k = quad*8 + u]
//   B[k = quad*8 + u][n = lane&15]
//   C/D: col = lane&15, row = quad*4 + reg

typedef __attribute__((ext_vector_type(4))) float f32x4;
typedef __attribute__((ext_vector_type(8))) short s16x8;
typedef __attribute__((ext_vector_type(4))) float float4v;

#define MFMA16(a, b, c) __builtin_amdgcn_mfma_f32_16x16x32_bf16((a), (b), (c), 0, 0, 0)

static constexpr int TL = 256, TH = 4;
// ws offsets in shorts (each buffer 512*4*256*16 = 8388608 elems = 16 MB)
static constexpr size_t NBUF  = (size_t)512 * 4 * 256 * 16;
static constexpr size_t QOFF  = 0;
static constexpr size_t KOFF  = NBUF;
static constexpr size_t VOFF  = 2 * NBUF;
static constexpr size_t GOFF  = 3 * NBUF;
static constexpr size_t GOOFF = 4 * NBUF;   // GO: [131072 rows][64 ch]

__device__ __forceinline__ short f2bf(float x) {   // fp32 -> bf16 RNE
    union { float f; unsigned u; } v; v.f = x;
    unsigned r = v.u + 0x7fffu + ((v.u >> 16) & 1u);
    return (short)(r >> 16);
}
__device__ __forceinline__ float bf2f(short s) {
    union { float f; unsigned u; } v; v.u = ((unsigned)(unsigned short)s) << 16;
    return v.f;
}
__device__ __forceinline__ s16x8 cvt8(const float* p) {  // 8 fp32 -> bf16x8
    s16x8 r;
    #pragma unroll
    for (int u = 0; u < 8; ++u) r[u] = f2bf(p[u]);
    return r;
}

// ---------------------------------------------------------------- kernel 1
__global__ __launch_bounds__(256, 4)
void k1_proj(const float* __restrict__ z, const float* __restrict__ ln_s,
             const float* __restrict__ ln_b, const float* __restrict__ Wq,
             const float* __restrict__ Wk, const float* __restrict__ Wv,
             const float* __restrict__ Wg, const float* __restrict__ bg,
             short* __restrict__ ws)
{
    __shared__ __align__(16) short znl[256 * 64];
    const int tid = threadIdx.x, lane = tid & 63, w = tid >> 6;
    const int n16 = lane & 15, quad = lane >> 4;
    const int bl = blockIdx.x;
    const size_t rowbase = (size_t)bl * (256 * 64);

    // ---- LN (thread = one position), bf16 -> LDS XOR-swizzled ----
    {
        float zn[64];
        const float* zp = z + rowbase + (size_t)tid * 64;
        float mu = 0.f;
        #pragma unroll
        for (int k = 0; k < 64; ++k) { zn[k] = zp[k]; mu += zn[k]; }
        mu *= (1.f / 64.f);
        float va = 0.f;
        #pragma unroll
        for (int k = 0; k < 64; ++k) { float d = zn[k] - mu; va += d * d; }
        const float rs = rsqrtf(va * (1.f / 64.f) + 1e-5f);
        #pragma unroll
        for (int k = 0; k < 64; ++k) zn[k] = (zn[k] - mu) * rs * ln_s[k] + ln_b[k];
        #pragma unroll
        for (int g = 0; g < 8; ++g) {
            s16x8 v;
            #pragma unroll
            for (int u = 0; u < 8; ++u) v[u] = f2bf(zn[g * 8 + u]);
            *(s16x8*)&znl[tid * 64 + ((g ^ (tid & 7)) * 8)] = v;
        }
    }
    __syncthreads();

    // ---- wave w computes projection type w for all heads ----
    const float* W = (w == 0) ? Wq : (w == 1) ? Wk : (w == 2) ? Wv : Wg;
    s16x8 bfr[4][2];                       // B-frags: [n-tile(head)][k-step]
    #pragma unroll
    for (int nt = 0; nt < 4; ++nt)
        #pragma unroll
        for (int ks = 0; ks < 2; ++ks)
            bfr[nt][ks] = cvt8(W + (size_t)(nt * 16 + n16) * 64 + ks * 32 + quad * 8);

    float bgv[4];
    #pragma unroll
    for (int nt = 0; nt < 4; ++nt) bgv[nt] = (w == 3) ? bg[nt * 16 + n16] : 0.f;

    short* qb = ws + QOFF;  short* kb = ws + KOFF;
    short* vb = ws + VOFF;  short* gb = ws + GOFF;

    for (int mt = 0; mt < 16; ++mt) {
        s16x8 a0 = *(const s16x8*)&znl[(mt * 16 + n16) * 64 + (((0 * 4 + quad) ^ (n16 & 7)) * 8)];
        s16x8 a1 = *(const s16x8*)&znl[(mt * 16 + n16) * 64 + (((1 * 4 + quad) ^ (n16 & 7)) * 8)];
        #pragma unroll
        for (int nt = 0; nt < 4; ++nt) {
            f32x4 acc = {};
            acc = MFMA16(a0, bfr[nt][0], acc);
            acc = MFMA16(a1, bfr[nt][1], acc);
            const size_t hb = (size_t)(bl * 4 + nt);
            if (w == 0) {                       // Q * 1/sqrt(16), [h][pos][16]
                #pragma unroll
                for (int r = 0; r < 4; ++r)
                    qb[(hb * 256 + mt * 16 + quad * 4 + r) * 16 + n16] = f2bf(0.25f * acc[r]);
            } else if (w == 1) {                // K, [h][pos][16]
                #pragma unroll
                for (int r = 0; r < 4; ++r)
                    kb[(hb * 256 + mt * 16 + quad * 4 + r) * 16 + n16] = f2bf(acc[r]);
            } else if (w == 2) {                // V transposed, [h][dh][pos]
                unsigned lo = (unsigned)(unsigned short)f2bf(acc[0]) |
                              ((unsigned)(unsigned short)f2bf(acc[1]) << 16);
                unsigned hi = (unsigned)(unsigned short)f2bf(acc[2]) |
                              ((unsigned)(unsigned short)f2bf(acc[3]) << 16);
                uint2 pk = {lo, hi};
                *(uint2*)&vb[(hb * 16 + n16) * 256 + mt * 16 + quad * 4] = pk;
            } else {                            // G = sigmoid(x + bg), [h][pos][16]
                #pragma unroll
                for (int r = 0; r < 4; ++r) {
                    float s = 1.f / (1.f + __expf(-(acc[r] + bgv[nt])));
                    gb[(hb * 256 + mt * 16 + quad * 4 + r) * 16 + n16] = f2bf(s);
                }
            }
        }
    }
}

// ---------------------------------------------------------------- kernel 2
// grid 2048 = (bl*4 + h); block 256 = 4 waves; wave w owns q-rows [w*64, w*64+64)
static constexpr int VSTRIDE = 264;   // Vt row stride (shorts), 16B-aligned rows
__global__ __launch_bounds__(256, 4)
void k2_attn(short* __restrict__ ws)
{
    __shared__ __align__(16) short Ksh[256 * 16];        // swizzled [pos][16]
    __shared__ __align__(16) short Vt[16 * VSTRIDE];     // [dh][pos]
    __shared__ __align__(16) short Pst[4][64 * 32];      // per-wave P chunk
    const int tid = threadIdx.x, lane = tid & 63, w = tid >> 6;
    const int n16 = lane & 15, quad = lane >> 4;
    const bool qlo = (quad < 2);
    const int g = blockIdx.x, bl = g >> 2, h = g & 3;

    const short* Qg = ws + QOFF + (size_t)g * 4096;
    const short* Kg = ws + KOFF + (size_t)g * 4096;
    const short* Vg = ws + VOFF + (size_t)g * 4096;
    const short* Gg = ws + GOFF + (size_t)g * 4096;
    short* GOg = ws + GOOFF;

    // ---- cooperative K, Vt staging ----
    #pragma unroll
    for (int e = 0; e < 2; ++e) {
        int flat = e * 256 + tid;
        int posk = flat >> 1, kh = flat & 1;
        s16x8 kv = *(const s16x8*)&Kg[posk * 16 + kh * 8];
        *(s16x8*)&Ksh[posk * 16 + ((kh ^ (posk & 1)) * 8)] = kv;
        int dh = flat >> 5, j0 = (flat & 31) * 8;
        s16x8 vv = *(const s16x8*)&Vg[dh * 256 + j0];
        *(s16x8*)&Vt[dh * VSTRIDE + j0] = vv;
    }
    __syncthreads();   // the ONLY barrier

    // ---- Q A-frags (quads 2,3 = zero: dh=16 < K=32) ----
    s16x8 qa[4];
    #pragma unroll
    for (int mt = 0; mt < 4; ++mt) {
        s16x8 q = {};
        if (qlo) q = *(const s16x8*)&Qg[(w * 64 + mt * 16 + n16) * 16 + quad * 8];
        qa[mt] = q;
    }

    // ---- pass 1: exact row max ----
    float mrow[4][4];
    #pragma unroll
    for (int mt = 0; mt < 4; ++mt)
        #pragma unroll
        for (int r = 0; r < 4; ++r) mrow[mt][r] = -3.0e38f;

    for (int jt = 0; jt < 16; ++jt) {
        int j = jt * 16 + n16;
        s16x8 kf = {};
        if (qlo) kf = *(const s16x8*)&Ksh[j * 16 + ((quad ^ (j & 1)) * 8)];
        #pragma unroll
        for (int mt = 0; mt < 4; ++mt) {
            f32x4 zc = {};
            f32x4 s = MFMA16(qa[mt], kf, zc);
            #pragma unroll
            for (int r = 0; r < 4; ++r) mrow[mt][r] = fmaxf(mrow[mt][r], s[r]);
        }
    }
    #pragma unroll
    for (int d = 1; d < 16; d <<= 1)
        #pragma unroll
        for (int mt = 0; mt < 4; ++mt)
            #pragma unroll
            for (int r = 0; r < 4; ++r)
                mrow[mt][r] = fmaxf(mrow[mt][r], __shfl_xor(mrow[mt][r], d));

    // ---- pass 2: P = exp(s-m) -> wave-private LDS -> PV (K=32 chunks) ----
    float lrow[4][4];
    f32x4 o4[4];
    #pragma unroll
    for (int mt = 0; mt < 4; ++mt) {
        o4[mt] = {};
        #pragma unroll
        for (int r = 0; r < 4; ++r) lrow[mt][r] = 0.f;
    }
    short* P = Pst[w];
    for (int ch = 0; ch < 8; ++ch) {
        #pragma unroll
        for (int jtl = 0; jtl < 2; ++jtl) {
            int j = ch * 32 + jtl * 16 + n16;
            s16x8 kf = {};
            if (qlo) kf = *(const s16x8*)&Ksh[j * 16 + ((quad ^ (j & 1)) * 8)];
            int jc = jtl * 16 + n16, jb = jc >> 3;
            #pragma unroll
            for (int mt = 0; mt < 4; ++mt) {
                f32x4 zc = {};
                f32x4 s = MFMA16(qa[mt], kf, zc);
                #pragma unroll
                for (int r = 0; r < 4; ++r) {
                    float e = __expf(s[r] - mrow[mt][r]);
                    lrow[mt][r] += e;
                    int rin = mt * 16 + quad * 4 + r;
                    P[rin * 32 + ((jb ^ (rin & 3)) * 8) + (jc & 7)] = f2bf(e);
                }
            }
        }
        // PV: A = P[64 x 32], B = Vt chunk [32 x 16]  (same-wave LDS RAW: DS in-order)
        #pragma unroll
        for (int mt = 0; mt < 4; ++mt) {
            int rin = mt * 16 + n16;
            s16x8 pa = *(const s16x8*)&P[rin * 32 + ((quad ^ (rin & 3)) * 8)];
            s16x8 vf = *(const s16x8*)&Vt[n16 * VSTRIDE + ch * 32 + quad * 8];
            o4[mt] = MFMA16(pa, vf, o4[mt]);
        }
    }
    #pragma unroll
    for (int d = 1; d < 16; d <<= 1)
        #pragma unroll
        for (int mt = 0; mt < 4; ++mt)
            #pragma unroll
            for (int r = 0; r < 4; ++r)
                lrow[mt][r] += __shfl_xor(lrow[mt][r], d);

    // ---- epilogue: gate * O / l -> GO bf16 [row][64] ----
    #pragma unroll
    for (int mt = 0; mt < 4; ++mt)
        #pragma unroll
        for (int r = 0; r < 4; ++r) {
            int pos = w * 64 + mt * 16 + quad * 4 + r;
            float gg = bf2f(Gg[pos * 16 + n16]);
            float go = gg * o4[mt][r] / lrow[mt][r];
            GOg[((size_t)bl * 256 + pos) * 64 + h * 16 + n16] = f2bf(go);
        }
}

// ---------------------------------------------------------------- kernel 3
// out = GO @ Wo^T + bo ; grid 512 blocks x 256 rows
__global__ __launch_bounds__(256, 4)
void k3_out(const short* __restrict__ ws, const float* __restrict__ Wo,
            const float* __restrict__ bo, float* __restrict__ out)
{
    const int tid = threadIdx.x, lane = tid & 63, w = tid >> 6;
    const int n16 = lane & 15, quad = lane >> 4;
    const short* GO = ws + GOOFF;
    const int rowbase = blockIdx.x * 256 + w * 64;

    s16x8 bfr[4][2];
    #pragma unroll
    for (int nt = 0; nt < 4; ++nt)
        #pragma unroll
        for (int ks = 0; ks < 2; ++ks)
            bfr[nt][ks] = cvt8(Wo + (size_t)(nt * 16 + n16) * 64 + ks * 32 + quad * 8);

    f32x4 acc[4][4] = {};
    #pragma unroll
    for (int mt = 0; mt < 4; ++mt) {
        const short* ap = &GO[(size_t)(rowbase + mt * 16 + n16) * 64];
        s16x8 a0 = *(const s16x8*)&ap[quad * 8];
        s16x8 a1 = *(const s16x8*)&ap[32 + quad * 8];
        #pragma unroll
        for (int nt = 0; nt < 4; ++nt) {
            acc[mt][nt] = MFMA16(a0, bfr[nt][0], acc[mt][nt]);
            acc[mt][nt] = MFMA16(a1, bfr[nt][1], acc[mt][nt]);
        }
    }
    #pragma unroll
    for (int nt = 0; nt < 4; ++nt) {
        float bov = bo[nt * 16 + n16];
        #pragma unroll
        for (int mt = 0; mt < 4; ++mt)
            #pragma unroll
            for (int r = 0; r < 4; ++r)
                out[(size_t)(rowbase + mt * 16 + quad * 4 + r) * 64 + nt * 16 + n16] =
                    acc[mt][nt][r] + bov;
    }
}

extern "C" void kernel_launch(void* const* d_in, const int* in_sizes, int n_in,
                              void* d_out, int out_size, void* d_ws, size_t ws_size,
                              hipStream_t stream) {
    const float* z  = (const float*)d_in[0];
    const float* ls = (const float*)d_in[1];
    const float* lb = (const float*)d_in[2];
    const float* Wq = (const float*)d_in[3];
    const float* Wk = (const float*)d_in[4];
    const float* Wv = (const float*)d_in[5];
    const float* Wg = (const float*)d_in[6];
    const float* bg = (const float*)d_in[7];
    const float* Wo = (const float*)d_in[8];
    const float* bo = (const float*)d_in[9];
    float* out = (float*)d_out;
    short* wsp = (short*)d_ws;

    hipLaunchKernelGGL(k1_proj, dim3(512), dim3(256), 0, stream,
                       z, ls, lb, Wq, Wk, Wv, Wg, bg, wsp);
    hipLaunchKernelGGL(k2_attn, dim3(2048), dim3(256), 0, stream, wsp);
    hipLaunchKernelGGL(k3_out, dim3(512), dim3(256), 0, stream, wsp, Wo, bo, out);
}